// Round 1
// baseline (446.231 us; speedup 1.0000x reference)
//
#include <hip/hip_runtime.h>
#include <hip/hip_bf16.h>

#define BB 65536
#define NFIELD 20
#define DATA_NEMB 10
#define SQL_NEMB 10
#define HID 64
#define KEXP 16
#define EPS 1e-5f
#define NBLK_GATE 256

// ---- ws layout (element offsets, 4B elements) ----
#define OFF_GCNT 0              // 16 int
#define OFF_SC1 64              // 16*64 f32
#define OFF_SH1 (OFF_SC1 + 1024)
#define OFF_SC2 (OFF_SH1 + 1024)
#define OFF_SH2 (OFF_SC2 + 1024)
#define OFF_SCP (OFF_SH2 + 1024) // 64
#define OFF_SHP (OFF_SCP + 64)   // 64
#define OFF_W2T (OFF_SHP + 64)   // 16*64*64 transposed e_w2
#define OFF_PW1T (OFF_W2T + 65536) // 64*64 transposed p_w1
#define OFF_IMP (OFF_PW1T + 4096)  // 256*16 importance partials
#define OFF_LIDX (OFF_IMP + 4096)  // 16*B int
#define OFF_LW (OFF_LIDX + (16 * BB)) // 16*B f32
#define OFF_HS (OFF_LW + (16 * BB))   // B*2*64 f32

// ---------------- prep: BN fold, transposes, counter zero ----------------
__global__ __launch_bounds__(256) void k_prep(
    const float* __restrict__ ew2, const float* __restrict__ pw1,
    const float* __restrict__ eb1, const float* __restrict__ eg1,
    const float* __restrict__ ebe1, const float* __restrict__ em1,
    const float* __restrict__ ev1,
    const float* __restrict__ eb2, const float* __restrict__ eg2,
    const float* __restrict__ ebe2, const float* __restrict__ em2,
    const float* __restrict__ ev2,
    const float* __restrict__ pb1, const float* __restrict__ pg,
    const float* __restrict__ pbe, const float* __restrict__ pm,
    const float* __restrict__ pv,
    float* __restrict__ wsf, int* __restrict__ gcnt)
{
    int gid = blockIdx.x * 256 + threadIdx.x;
    if (gid < 65536) {
        // W2t[k][h][i] = ew2[k][i][h]
        int k = gid >> 12, r = gid & 4095, h = r >> 6, i = r & 63;
        wsf[OFF_W2T + gid] = ew2[(k * HID + i) * HID + h];
    } else if (gid < 65536 + 4096) {
        int t = gid - 65536;
        int h = t >> 6, i = t & 63;
        wsf[OFF_PW1T + t] = pw1[i * HID + h];
    } else if (gid < 65536 + 4096 + 1024) {
        int t = gid - (65536 + 4096); // k*64+h
        float rs1 = rsqrtf(ev1[t] + EPS) * eg1[t];
        wsf[OFF_SC1 + t] = rs1;
        wsf[OFF_SH1 + t] = fmaf(eb1[t] - em1[t], rs1, ebe1[t]);
        float rs2 = rsqrtf(ev2[t] + EPS) * eg2[t];
        wsf[OFF_SC2 + t] = rs2;
        wsf[OFF_SH2 + t] = fmaf(eb2[t] - em2[t], rs2, ebe2[t]);
    } else if (gid < 65536 + 4096 + 1024 + 64) {
        int t = gid - (65536 + 4096 + 1024);
        float rs = rsqrtf(pv[t] + EPS) * pg[t];
        wsf[OFF_SCP + t] = rs;
        wsf[OFF_SHP + t] = fmaf(pb1[t] - pm[t], rs, pbe[t]);
    } else if (gid < 65536 + 4096 + 1024 + 64 + 16) {
        gcnt[gid - (65536 + 4096 + 1024 + 64)] = 0;
    }
}

// ---------------- gate: MLP + softmax + top2 + list build ----------------
__global__ __launch_bounds__(256) void k_gate(
    const int* __restrict__ sql, const float* __restrict__ sql_table,
    const float* __restrict__ gw1, const float* __restrict__ gb1,
    const float* __restrict__ gw2, const float* __restrict__ gb2,
    int* __restrict__ lidx, float* __restrict__ lw,
    int* __restrict__ gcnt, float* __restrict__ imp_part)
{
    __shared__ float s_imp[KEXP];
    __shared__ int s_cnt[KEXP];
    __shared__ int s_base[KEXP];
    int tid = threadIdx.x;
    if (tid < KEXP) { s_imp[tid] = 0.f; s_cnt[tid] = 0; }
    __syncthreads();

    int b = blockIdx.x * 256 + tid;
    float acc[HID];
#pragma unroll
    for (int h = 0; h < HID; ++h) acc[h] = 0.f;
    for (int f = 0; f < NFIELD; ++f) {
        int c = sql[b * NFIELD + f];
        const float* row = sql_table + c * SQL_NEMB;
        float xv[SQL_NEMB];
#pragma unroll
        for (int j = 0; j < SQL_NEMB / 2; ++j) {
            float2 t = *(const float2*)(row + 2 * j);
            xv[2 * j] = t.x; xv[2 * j + 1] = t.y;
        }
#pragma unroll
        for (int i = 0; i < SQL_NEMB; ++i) {
            const float* wr = gw1 + (f * SQL_NEMB + i) * HID;
#pragma unroll
            for (int h = 0; h < HID; ++h) acc[h] = fmaf(xv[i], wr[h], acc[h]);
        }
    }
    float z[KEXP];
#pragma unroll
    for (int j = 0; j < KEXP; ++j) z[j] = gb2[j];
#pragma unroll
    for (int h = 0; h < HID; ++h) {
        float g = fmaxf(acc[h] + gb1[h], 0.f);
#pragma unroll
        for (int j = 0; j < KEXP; ++j) z[j] = fmaf(g, gw2[h * KEXP + j], z[j]);
    }
    // softmax denom
    float m = z[0];
#pragma unroll
    for (int j = 1; j < KEXP; ++j) m = fmaxf(m, z[j]);
    float s = 0.f;
#pragma unroll
    for (int j = 0; j < KEXP; ++j) s += expf(z[j] - m);
    // top-2 on logits (softmax is monotone)
    int i0 = 0; float m0 = z[0];
#pragma unroll
    for (int j = 1; j < KEXP; ++j) if (z[j] > m0) { m0 = z[j]; i0 = j; }
    int i1 = (i0 == 0) ? 1 : 0; float m1 = -3.4e38f;
#pragma unroll
    for (int j = 0; j < KEXP; ++j) if (j != i0 && z[j] > m1) { m1 = z[j]; i1 = j; }
    float v0 = expf(m0 - m) / s, v1 = expf(m1 - m) / s;
    float inv = 1.f / (v0 + v1 + 1e-9f);
    float w0 = v0 * inv, w1 = v1 * inv;

    atomicAdd(&s_imp[i0], w0);
    atomicAdd(&s_imp[i1], w1);
    int o0 = atomicAdd(&s_cnt[i0], 1);
    int o1 = atomicAdd(&s_cnt[i1], 1);
    __syncthreads();
    if (tid < KEXP) {
        imp_part[blockIdx.x * KEXP + tid] = s_imp[tid];
        s_base[tid] = atomicAdd(&gcnt[tid], s_cnt[tid]);
    }
    __syncthreads();
    int p0 = i0 * BB + s_base[i0] + o0;
    lidx[p0] = (b << 1);     lw[p0] = w0;
    int p1 = i1 * BB + s_base[i1] + o1;
    lidx[p1] = (b << 1) | 1; lw[p1] = w1;
}

// ---------------- loss from importance partials ----------------
__global__ void k_loss(const float* __restrict__ imp_part, float* __restrict__ out)
{
    __shared__ double simp[KEXP];
    int tid = threadIdx.x;
    if (tid < KEXP) {
        double s = 0.0;
        for (int blk = 0; blk < NBLK_GATE; ++blk) s += (double)imp_part[blk * KEXP + tid];
        simp[tid] = s;
    }
    __syncthreads();
    if (tid == 0) {
        double mean = 0.0;
        for (int j = 0; j < KEXP; ++j) mean += simp[j];
        mean /= KEXP;
        double var = 0.0;
        for (int j = 0; j < KEXP; ++j) { double d = simp[j] - mean; var += d * d; }
        var /= KEXP;
        out[BB] = (float)(var / (mean * mean + 1e-10));
    }
}

// ---------------- expert MLP over its sample list ----------------
__global__ __launch_bounds__(256) void k_expert(
    const int* __restrict__ x, const float* __restrict__ itab,
    const float* __restrict__ ew1,
    const float* __restrict__ w2t,
    const float* __restrict__ sc1, const float* __restrict__ sh1,
    const float* __restrict__ sc2, const float* __restrict__ sh2,
    const int* __restrict__ lidx, const float* __restrict__ lw,
    const int* __restrict__ gcnt, float* __restrict__ hs)
{
    int k = blockIdx.y;
    int n = gcnt[k];
    const float* W1 = ew1 + k * (NFIELD * DATA_NEMB * HID);
    const float* W2T = w2t + k * (HID * HID);
    for (int idx = blockIdx.x * blockDim.x + threadIdx.x; idx < n;
         idx += gridDim.x * blockDim.x) {
        int e = lidx[k * BB + idx];
        float w = lw[k * BB + idx];
        int b = e >> 1, slot = e & 1;

        float acc[HID];
#pragma unroll
        for (int h = 0; h < HID; ++h) acc[h] = 0.f;
        for (int f = 0; f < NFIELD; ++f) {
            int c = x[b * NFIELD + f];
            const float* row = itab + c * DATA_NEMB;
            float xv[DATA_NEMB];
#pragma unroll
            for (int j = 0; j < DATA_NEMB / 2; ++j) {
                float2 t = *(const float2*)(row + 2 * j);
                xv[2 * j] = t.x; xv[2 * j + 1] = t.y;
            }
#pragma unroll
            for (int i = 0; i < DATA_NEMB; ++i) {
                const float* wr = W1 + (f * DATA_NEMB + i) * HID;
#pragma unroll
                for (int h = 0; h < HID; ++h) acc[h] = fmaf(xv[i], wr[h], acc[h]);
            }
        }
        float h1[HID];
#pragma unroll
        for (int h = 0; h < HID; ++h)
            h1[h] = fmaxf(fmaf(acc[h], sc1[k * HID + h], sh1[k * HID + h]), 0.f);

        float* outp = hs + ((size_t)b * 2 + slot) * HID;
        for (int h0 = 0; h0 < HID / 4; ++h0) { // runtime loop, 4 outputs/iter
            float t4[4];
#pragma unroll
            for (int u = 0; u < 4; ++u) {
                float t = 0.f;
                const float* wr = W2T + (h0 * 4 + u) * HID;
#pragma unroll
                for (int i = 0; i < HID; ++i) t = fmaf(h1[i], wr[i], t);
                int h = h0 * 4 + u;
                t4[u] = w * fmaxf(fmaf(t, sc2[k * HID + h], sh2[k * HID + h]), 0.f);
            }
            float4 v; v.x = t4[0]; v.y = t4[1]; v.z = t4[2]; v.w = t4[3];
            *(float4*)(outp + h0 * 4) = v;
        }
    }
}

// ---------------- predict head ----------------
__global__ __launch_bounds__(256) void k_head(
    const float* __restrict__ hs, const float* __restrict__ pw1t,
    const float* __restrict__ scp, const float* __restrict__ shp,
    const float* __restrict__ pw2, const float* __restrict__ pb2,
    float* __restrict__ out)
{
    int b = blockIdx.x * 256 + threadIdx.x;
    const float* hp = hs + (size_t)b * 128;
    float y[HID];
#pragma unroll
    for (int j = 0; j < HID / 4; ++j) {
        float4 a = *(const float4*)(hp + 4 * j);
        float4 c = *(const float4*)(hp + 64 + 4 * j);
        y[4 * j] = a.x + c.x; y[4 * j + 1] = a.y + c.y;
        y[4 * j + 2] = a.z + c.z; y[4 * j + 3] = a.w + c.w;
    }
    float o = pb2[0];
    for (int h = 0; h < HID; ++h) { // runtime loop
        float t = 0.f;
        const float* wr = pw1t + h * HID;
#pragma unroll
        for (int i = 0; i < HID; ++i) t = fmaf(y[i], wr[i], t);
        float ph = fmaxf(fmaf(t, scp[h], shp[h]), 0.f);
        o = fmaf(ph, pw2[h], o);
    }
    out[b] = o;
}

extern "C" void kernel_launch(void* const* d_in, const int* in_sizes, int n_in,
                              void* d_out, int out_size, void* d_ws, size_t ws_size,
                              hipStream_t stream) {
    const int*   x     = (const int*)d_in[0];
    const int*   sql   = (const int*)d_in[1];
    const float* itab  = (const float*)d_in[2];
    const float* stab  = (const float*)d_in[3];
    const float* gw1   = (const float*)d_in[4];
    const float* gb1   = (const float*)d_in[5];
    const float* gw2   = (const float*)d_in[6];
    const float* gb2   = (const float*)d_in[7];
    const float* ew1   = (const float*)d_in[8];
    const float* eb1   = (const float*)d_in[9];
    const float* eg1   = (const float*)d_in[10];
    const float* ebe1  = (const float*)d_in[11];
    const float* em1   = (const float*)d_in[12];
    const float* ev1   = (const float*)d_in[13];
    const float* ew2   = (const float*)d_in[14];
    const float* eb2   = (const float*)d_in[15];
    const float* eg2   = (const float*)d_in[16];
    const float* ebe2  = (const float*)d_in[17];
    const float* em2   = (const float*)d_in[18];
    const float* ev2   = (const float*)d_in[19];
    const float* pw1   = (const float*)d_in[20];
    const float* pb1   = (const float*)d_in[21];
    const float* pg    = (const float*)d_in[22];
    const float* pbe   = (const float*)d_in[23];
    const float* pm    = (const float*)d_in[24];
    const float* pv    = (const float*)d_in[25];
    const float* pw2   = (const float*)d_in[26];
    const float* pb2   = (const float*)d_in[27];

    float* wsf  = (float*)d_ws;
    int*   wsi  = (int*)d_ws;
    int*   gcnt = wsi + OFF_GCNT;
    float* sc1  = wsf + OFF_SC1;
    float* sh1  = wsf + OFF_SH1;
    float* sc2  = wsf + OFF_SC2;
    float* sh2  = wsf + OFF_SH2;
    float* scp  = wsf + OFF_SCP;
    float* shp  = wsf + OFF_SHP;
    float* w2t  = wsf + OFF_W2T;
    float* pw1t = wsf + OFF_PW1T;
    float* imp  = wsf + OFF_IMP;
    int*   lidx = wsi + OFF_LIDX;
    float* lw   = wsf + OFF_LW;
    float* hs   = wsf + OFF_HS;
    float* out  = (float*)d_out;

    k_prep<<<277, 256, 0, stream>>>(ew2, pw1, eb1, eg1, ebe1, em1, ev1,
                                    eb2, eg2, ebe2, em2, ev2,
                                    pb1, pg, pbe, pm, pv, wsf, gcnt);
    k_gate<<<NBLK_GATE, 256, 0, stream>>>(sql, stab, gw1, gb1, gw2, gb2,
                                          lidx, lw, gcnt, imp);
    k_loss<<<1, 64, 0, stream>>>(imp, out);
    dim3 g3(32, KEXP);
    k_expert<<<g3, 256, 0, stream>>>(x, itab, ew1, w2t, sc1, sh1, sc2, sh2,
                                     lidx, lw, gcnt, hs);
    k_head<<<NBLK_GATE, 256, 0, stream>>>(hs, pw1t, scp, shp, pw2, pb2, out);
}